// Round 3
// baseline (133.318 us; speedup 1.0000x reference)
//
#include <hip/hip_runtime.h>
#include <hip/hip_bf16.h>

#define TD 10          // tree depth
#define NCOL 256       // input dim
#define ROWS_PER_BLOCK 256
#define CHUNK_COLS 32  // columns staged per chunk (128B per row = 1 L2 line)
#define NCHUNK (NCOL / CHUNK_COLS)   // 8

// ---- DFS fold over the leaf tree, terminated at level TD-3 (8-leaf groups) ----
// LEVEL 0 = MSB (d=0). bit 0 -> q[d], bit 1 -> p[d].
// g[o] = t7*t8*t9 with o = (bit7<<2)|(bit8<<1)|bit9, precomputed once.
template <int LEVEL, int IDX>
__device__ __forceinline__ void fold(const float* __restrict__ lv,
                                     const float (&p)[TD], const float (&q)[TD],
                                     const float (&g)[8],
                                     float prefix, float& acc) {
  if constexpr (LEVEL == TD - 3) {
    const float* l8 = lv + 8 * IDX;          // leaves visited sequentially
    float t = l8[0] * g[0];
    t = fmaf(l8[1], g[1], t);
    t = fmaf(l8[2], g[2], t);
    t = fmaf(l8[3], g[3], t);
    t = fmaf(l8[4], g[4], t);
    t = fmaf(l8[5], g[5], t);
    t = fmaf(l8[6], g[6], t);
    t = fmaf(l8[7], g[7], t);
    acc = fmaf(prefix, t, acc);
  } else {
    fold<LEVEL + 1, 2 * IDX>(lv, p, q, g, prefix * q[LEVEL], acc);
    fold<LEVEL + 1, 2 * IDX + 1>(lv, p, q, g, prefix * p[LEVEL], acc);
  }
}

__global__ void __launch_bounds__(256, 4)
odt_kernel(const float* __restrict__ x, const float* __restrict__ W,
           const float* __restrict__ bias, const float* __restrict__ lv,
           float* __restrict__ out) {
  // per-wave private SINGLE-buffer staging: [wave][64 rows * 32 cols] = 8KB/wave.
  // 32KB/block -> 4 blocks/CU (grid = 1024 = 4/CU exact co-residency).
  // Safe without double-buffer: per-wave DS ops execute in order, and the
  // chunk's ds_reads are issued before chunk+1's overwriting ds_writes.
  __shared__ float xs[4][64 * CHUNK_COLS];

  const int lane = threadIdx.x & 63;
  const int wave = threadIdx.x >> 6;
  const int row0 = blockIdx.x * ROWS_PER_BLOCK + wave * 64;  // wave's first row
  const float* __restrict__ xw = x + (size_t)row0 * NCOL;

  // Reg-staged global->LDS (T14): global loads are CONTIGUOUS 128B per row
  // (one L2 line per segment); the transpose-ish XOR swizzle happens on the
  // ds_write side (scatter is free there, unlike global_load_lds).
  // Instruction j: row r = j*8 + (lane>>3), granule g = lane&7 (16B granules).
  const int rsub = lane >> 3;      // row-within-octet, == r & 7
  const int gran = lane & 7;       // column granule (4 floats)
  const int swz  = (gran ^ rsub) << 2;              // stored granule offset (floats)
  const size_t gsrc = (size_t)(lane >> 3) * NCOL + gran * 4;  // per-lane row/col base
  float* __restrict__ xsw = xs[wave];

  float4 rbuf[8];

  // prologue: load chunk 0 into regs, write to LDS
#pragma unroll
  for (int j = 0; j < 8; ++j)
    rbuf[j] = *(const float4*)(xw + (size_t)j * 8 * NCOL + gsrc);
#pragma unroll
  for (int j = 0; j < 8; ++j)
    *(float4*)&xsw[(j * 8 + rsub) * CHUNK_COLS + swz] = rbuf[j];

  float sums[TD];
#pragma unroll
  for (int d = 0; d < TD; ++d) sums[d] = bias[d];  // uniform -> s_load

  for (int chunk = 0; chunk < NCHUNK; ++chunk) {
    // issue next chunk's global loads FIRST (prefetch; ~8KB/wave in flight)
    if (chunk < NCHUNK - 1) {
#pragma unroll
      for (int j = 0; j < 8; ++j)
        rbuf[j] = *(const float4*)(xw + (size_t)j * 8 * NCOL +
                                   (chunk + 1) * CHUNK_COLS + gsrc);
    }
    // consume current chunk from LDS (thread-per-row; W reads wave-uniform)
#pragma unroll
    for (int i = 0; i < CHUNK_COLS / 4; ++i) {
      const float4 xv = *(const float4*)&xsw[lane * CHUNK_COLS +
                                             ((i ^ (lane & 7)) << 2)];
#pragma unroll
      for (int e = 0; e < 4; ++e) {
        const float xe = (&xv.x)[e];
        const int col = chunk * CHUNK_COLS + i * 4 + e;  // uniform
#pragma unroll
        for (int d = 0; d < TD; ++d)
          sums[d] = fmaf(xe, W[col * TD + d], sums[d]);  // W uniform -> s_load
      }
    }
    // write next chunk to LDS (compiler inserts the vmcnt wait on rbuf here)
    if (chunk < NCHUNK - 1) {
#pragma unroll
      for (int j = 0; j < 8; ++j)
        *(float4*)&xsw[(j * 8 + rsub) * CHUNK_COLS + swz] = rbuf[j];
    }
  }

  // sigmoid
  float p[TD], q[TD];
#pragma unroll
  for (int d = 0; d < TD; ++d) {
    const float s = 1.0f / (1.0f + __expf(-sums[d]));
    p[d] = s;
    q[d] = 1.0f - s;
  }

  // precompute last-3-level products: g[o] = t7[o>>2] * t8[(o>>1)&1] * t9[o&1]
  float g[8];
  {
    const float h00 = q[8] * q[9], h01 = q[8] * p[9];
    const float h10 = p[8] * q[9], h11 = p[8] * p[9];
    g[0] = q[7] * h00; g[1] = q[7] * h01; g[2] = q[7] * h10; g[3] = q[7] * h11;
    g[4] = p[7] * h00; g[5] = p[7] * h01; g[6] = p[7] * h10; g[7] = p[7] * h11;
  }

  // weighted-leaf contraction: DFS over levels 0..6 (127 nodes, 254 muls),
  // then 128 x 8-leaf groups (9 ops each) => ~1430 VALU ops total
  float acc = 0.0f;
  fold<0, 0>(lv, p, q, g, 1.0f, acc);

  out[row0 + lane] = acc;
}

extern "C" void kernel_launch(void* const* d_in, const int* in_sizes, int n_in,
                              void* d_out, int out_size, void* d_ws, size_t ws_size,
                              hipStream_t stream) {
  const float* x = (const float*)d_in[0];
  const float* W = (const float*)d_in[1];
  const float* b = (const float*)d_in[2];
  const float* lv = (const float*)d_in[3];
  float* out = (float*)d_out;

  const int batch = in_sizes[0] / NCOL;          // 262144
  const int grid = batch / ROWS_PER_BLOCK;       // 1024
  odt_kernel<<<grid, 256, 0, stream>>>(x, W, b, lv, out);
}

// Round 4
// 84.704 us; speedup vs baseline: 1.5739x; 1.5739x over previous
//
#include <hip/hip_runtime.h>
#include <hip/hip_bf16.h>

#define TD 10          // tree depth
#define NCOL 256       // input dim
#define ROWS_PER_BLOCK 256
#define CHUNK_COLS 16  // columns staged per chunk
#define NCHUNK (NCOL / CHUNK_COLS)   // 16
#define NBUF 3         // triple buffer: prefetch 2 chunks ahead

// ---- async global->LDS (16B per lane), dest is wave-uniform base + lane*16 ----
typedef const __attribute__((address_space(1))) void* as1_cvp;
typedef __attribute__((address_space(3))) void* as3_vp;

__device__ __forceinline__ void gload_lds16(const float* g, float* l) {
  __builtin_amdgcn_global_load_lds((as1_cvp)(const void*)g, (as3_vp)(void*)l, 16, 0, 0);
}

// ---- DFS fold over the leaf tree, terminated at level TD-4 (16-leaf groups) ----
// LEVEL 0 = MSB (d=0). bit 0 -> q[d], bit 1 -> p[d].
// g[o] = t6*t7*t8*t9 with o = (b6<<3)|(b7<<2)|(b8<<1)|b9, precomputed once.
template <int LEVEL, int IDX>
__device__ __forceinline__ void fold(const float* __restrict__ lv,
                                     const float (&p)[TD], const float (&q)[TD],
                                     const float (&g)[16],
                                     float prefix, float& acc) {
  if constexpr (LEVEL == TD - 4) {
    const float* l16 = lv + 16 * IDX;        // leaves visited sequentially
    float t = l16[0] * g[0];
#pragma unroll
    for (int k = 1; k < 16; ++k) t = fmaf(l16[k], g[k], t);
    acc = fmaf(prefix, t, acc);
  } else {
    fold<LEVEL + 1, 2 * IDX>(lv, p, q, g, prefix * q[LEVEL], acc);
    fold<LEVEL + 1, 2 * IDX + 1>(lv, p, q, g, prefix * p[LEVEL], acc);
  }
}

__global__ void __launch_bounds__(256, 3)
odt_kernel(const float* __restrict__ x, const float* __restrict__ W,
           const float* __restrict__ bias, const float* __restrict__ lv,
           float* __restrict__ out) {
  // per-wave private TRIPLE-buffered staging: [wave][buf][64 rows * 16 cols]
  // 48 KiB/block -> 3 blocks/CU; each wave keeps 2 chunks (8KB) in flight.
  __shared__ float xs[4][NBUF][64 * CHUNK_COLS];

  const int lane = threadIdx.x & 63;
  const int wave = threadIdx.x >> 6;
  const int row0 = blockIdx.x * ROWS_PER_BLOCK + wave * 64;  // wave's first row
  const float* __restrict__ xw = x + (size_t)row0 * NCOL;

  // LDS fill is linear (instr i, lane l -> words i*256 + l*4..+3).
  // Pre-swizzle the GLOBAL source so stored layout is:
  //   word(r, j*4+e) = col (((j ^ (r&3))<<2)+e),  j = lane&3
  auto stage = [&](int chunk, int buf) {
    const float* src0 = xw + chunk * CHUNK_COLS;
#pragma unroll
    for (int i = 0; i < 4; ++i) {
      const int r = i * 16 + (lane >> 2);
      const int c = ((lane & 3) ^ (r & 3)) << 2;
      gload_lds16(src0 + (size_t)r * NCOL + c, &xs[wave][buf][i * 256]);
    }
  };

  float sums[TD];
#pragma unroll
  for (int d = 0; d < TD; ++d) sums[d] = bias[d];  // uniform -> s_load

  stage(0, 0);
  stage(1, 1);

#pragma unroll
  for (int chunk = 0; chunk < NCHUNK; ++chunk) {
    if (chunk < NCHUNK - 2) {
      stage(chunk + 2, (chunk + 2) % NBUF);
      // outstanding <= 12 (chunks c,c+1,c+2); wait until <=8 -> chunk c done
      asm volatile("s_waitcnt vmcnt(8)" ::: "memory");
    } else if (chunk == NCHUNK - 2) {
      asm volatile("s_waitcnt vmcnt(4)" ::: "memory");  // chunk c done
    } else {
      asm volatile("s_waitcnt vmcnt(0)" ::: "memory");  // last chunk done
    }
    const float* __restrict__ xb = xs[wave][chunk % NBUF];
#pragma unroll
    for (int c4 = 0; c4 < CHUNK_COLS / 4; ++c4) {
      const float4 xv = *(const float4*)&xb[lane * CHUNK_COLS +
                                            ((c4 ^ (lane & 3)) << 2)];
#pragma unroll
      for (int e = 0; e < 4; ++e) {
        const float xe = (&xv.x)[e];
        const int col = chunk * CHUNK_COLS + c4 * 4 + e;  // uniform
#pragma unroll
        for (int d = 0; d < TD; ++d)
          sums[d] = fmaf(xe, W[col * TD + d], sums[d]);  // W uniform -> s_load
      }
    }
  }

  // sigmoid
  float p[TD], q[TD];
#pragma unroll
  for (int d = 0; d < TD; ++d) {
    const float s = 1.0f / (1.0f + __expf(-sums[d]));
    p[d] = s;
    q[d] = 1.0f - s;
  }

  // precompute last-4-level products:
  // g[o] = t6[o>>3] * t7[(o>>2)&1] * t8[(o>>1)&1] * t9[o&1]
  float g[16];
  {
    float hA[4], hB[4];
    hA[0] = q[6] * q[7]; hA[1] = q[6] * p[7]; hA[2] = p[6] * q[7]; hA[3] = p[6] * p[7];
    hB[0] = q[8] * q[9]; hB[1] = q[8] * p[9]; hB[2] = p[8] * q[9]; hB[3] = p[8] * p[9];
#pragma unroll
    for (int o = 0; o < 16; ++o) g[o] = hA[o >> 2] * hB[o & 3];
  }

  // weighted-leaf contraction: DFS over levels 0..5 (63 nodes, 126 muls),
  // then 64 x 16-leaf groups (17 ops each) + 24 setup => ~1240 VALU ops
  float acc = 0.0f;
  fold<0, 0>(lv, p, q, g, 1.0f, acc);

  out[row0 + lane] = acc;
}

extern "C" void kernel_launch(void* const* d_in, const int* in_sizes, int n_in,
                              void* d_out, int out_size, void* d_ws, size_t ws_size,
                              hipStream_t stream) {
  const float* x = (const float*)d_in[0];
  const float* W = (const float*)d_in[1];
  const float* b = (const float*)d_in[2];
  const float* lv = (const float*)d_in[3];
  float* out = (float*)d_out;

  const int batch = in_sizes[0] / NCOL;          // 262144
  const int grid = batch / ROWS_PER_BLOCK;       // 1024
  odt_kernel<<<grid, 256, 0, stream>>>(x, W, b, lv, out);
}

// Round 5
// 64.639 us; speedup vs baseline: 2.0625x; 1.3104x over previous
//
#include <hip/hip_runtime.h>
#include <hip/hip_bf16.h>

#define TD 10          // tree depth
#define NCOL 256       // input dim
#define GCOLS 32       // cols per group = 128 B per row = one full L2 line
#define NGRP (NCOL / GCOLS)  // 8

// ---- DFS fold over the leaf tree, terminated at level TD-4 (16-leaf groups) ----
// LEVEL 0 = MSB (d=0). bit 0 -> q[d], bit 1 -> p[d].
// g[o] = t6*t7*t8*t9 with o = (b6<<3)|(b7<<2)|(b8<<1)|b9, precomputed once.
template <int LEVEL, int IDX>
__device__ __forceinline__ void fold(const float* __restrict__ lv,
                                     const float (&p)[TD], const float (&q)[TD],
                                     const float (&g)[16],
                                     float prefix, float& acc) {
  if constexpr (LEVEL == TD - 4) {
    const float* l16 = lv + 16 * IDX;        // leaves visited sequentially
    float t = l16[0] * g[0];
#pragma unroll
    for (int k = 1; k < 16; ++k) t = fmaf(l16[k], g[k], t);
    acc = fmaf(prefix, t, acc);
  } else {
    fold<LEVEL + 1, 2 * IDX>(lv, p, q, g, prefix * q[LEVEL], acc);
    fold<LEVEL + 1, 2 * IDX + 1>(lv, p, q, g, prefix * p[LEVEL], acc);
  }
}

__global__ void __launch_bounds__(256, 4)
odt_kernel(const float* __restrict__ x, const float* __restrict__ W,
           const float* __restrict__ bias, const float* __restrict__ lv,
           float* __restrict__ out) {
  // Pure register pipeline — no LDS. Each thread streams its own 1 KB row
  // through a ping-pong buffer of 2 x 8 float4 (one 128 B line per group).
  // ALL loops touching buf are fully unrolled => every index is a compile-time
  // constant => registers, not scratch (rule-of-R3).
  const int row = blockIdx.x * 256 + threadIdx.x;
  const float* __restrict__ xr = x + (size_t)row * NCOL;

  float4 buf[2][8];
#pragma unroll
  for (int j = 0; j < 8; ++j)
    buf[0][j] = *(const float4*)(xr + 4 * j);          // group 0: cols 0..31

  float sums[TD];
#pragma unroll
  for (int d = 0; d < TD; ++d) sums[d] = bias[d];      // uniform -> s_load

#pragma unroll
  for (int g = 0; g < NGRP; ++g) {
    // prefetch next group into the other buffer (in flight across this
    // group's 320 FMAs; compiler places the waitcnt before first use)
    if (g + 1 < NGRP) {
#pragma unroll
      for (int j = 0; j < 8; ++j)
        buf[(g + 1) & 1][j] =
            *(const float4*)(xr + (g + 1) * GCOLS + 4 * j);
    }
#pragma unroll
    for (int j = 0; j < 8; ++j) {
#pragma unroll
      for (int e = 0; e < 4; ++e) {
        const float xe = (&buf[g & 1][j].x)[e];
        const int col = g * GCOLS + 4 * j + e;         // compile-time constant
#pragma unroll
        for (int d = 0; d < TD; ++d)
          sums[d] = fmaf(xe, W[col * TD + d], sums[d]); // W uniform -> s_load
      }
    }
  }

  // sigmoid
  float p[TD], q[TD];
#pragma unroll
  for (int d = 0; d < TD; ++d) {
    const float s = 1.0f / (1.0f + __expf(-sums[d]));
    p[d] = s;
    q[d] = 1.0f - s;
  }

  // precompute last-4-level products:
  // g[o] = t6[o>>3] * t7[(o>>2)&1] * t8[(o>>1)&1] * t9[o&1]
  float g[16];
  {
    float hA[4], hB[4];
    hA[0] = q[6] * q[7]; hA[1] = q[6] * p[7]; hA[2] = p[6] * q[7]; hA[3] = p[6] * p[7];
    hB[0] = q[8] * q[9]; hB[1] = q[8] * p[9]; hB[2] = p[8] * q[9]; hB[3] = p[8] * p[9];
#pragma unroll
    for (int o = 0; o < 16; ++o) g[o] = hA[o >> 2] * hB[o & 3];
  }

  // weighted-leaf contraction: DFS over levels 0..5 (63 nodes, 126 muls),
  // then 64 x 16-leaf groups (17 ops each) + 24 setup => ~1240 VALU ops
  float acc = 0.0f;
  fold<0, 0>(lv, p, q, g, 1.0f, acc);

  out[row] = acc;
}

extern "C" void kernel_launch(void* const* d_in, const int* in_sizes, int n_in,
                              void* d_out, int out_size, void* d_ws, size_t ws_size,
                              hipStream_t stream) {
  const float* x = (const float*)d_in[0];
  const float* W = (const float*)d_in[1];
  const float* b = (const float*)d_in[2];
  const float* lv = (const float*)d_in[3];
  float* out = (float*)d_out;

  const int batch = in_sizes[0] / NCOL;   // 262144
  const int grid = batch / 256;           // 1024 blocks = 4/CU exactly
  odt_kernel<<<grid, 256, 0, stream>>>(x, W, b, lv, out);
}